// Round 11
// baseline (1856.147 us; speedup 1.0000x reference)
//
#include <hip/hip_runtime.h>
#include <hip/hip_bf16.h>
#include <math.h>

#define B 4
#define S 2048
#define H 768
#define V 32000
#define HID 100
#define G4 400   // 4*HID
#define M_TOT (B*S)
#define PD 2     // xproj prefetch depth (steps)
#define NTILE 7  // max M-tiles (of 16 rows) per wave: 25 tiles over 4 waves

typedef _Float16 half2_t __attribute__((ext_vector_type(2)));
typedef _Float16 half8_t __attribute__((ext_vector_type(8)));
typedef float float4_t __attribute__((ext_vector_type(4)));

__device__ __forceinline__ float sigmoidf_(float x) {
  return 1.0f / (1.0f + __expf(-x));
}

// Raw workgroup barrier: orders LDS (lgkmcnt drain) but does NOT drain vmcnt,
// so global prefetch loads stay in flight across steps.
__device__ __forceinline__ void lds_barrier_() {
  asm volatile("s_waitcnt lgkmcnt(0)" ::: "memory");
  __builtin_amdgcn_s_barrier();
  asm volatile("" ::: "memory");
}

// ---------------- Kernel 1: surprisal (online softmax + gather) --------------
__global__ __launch_bounds__(256) void surprisal_kernel(
    const float* __restrict__ logits, const int* __restrict__ ids,
    const float* __restrict__ mask, float* __restrict__ surp) {
  int row = blockIdx.x;
  const float* x = logits + (size_t)row * V;
  int tid = threadIdx.x;
  float m = -INFINITY, s = 0.0f;
  const float4* x4 = (const float4*)x;
  for (int i = tid; i < V / 4; i += 256) {
    float4 v = x4[i];
    float mv = fmaxf(fmaxf(v.x, v.y), fmaxf(v.z, v.w));
    if (mv > m) { s *= __expf(m - mv); m = mv; }
    s += __expf(v.x - m) + __expf(v.y - m) + __expf(v.z - m) + __expf(v.w - m);
  }
  #pragma unroll
  for (int off = 32; off > 0; off >>= 1) {
    float mo = __shfl_xor(m, off);
    float so = __shfl_xor(s, off);
    float mn = fmaxf(m, mo);
    s = s * __expf(m - mn) + so * __expf(mo - mn);
    m = mn;
  }
  __shared__ float sm[4], ss[4];
  int wid = tid >> 6, lane = tid & 63;
  if (lane == 0) { sm[wid] = m; ss[wid] = s; }
  __syncthreads();
  if (tid == 0) {
    float M = sm[0], Ssum = ss[0];
    #pragma unroll
    for (int w = 1; w < 4; ++w) {
      float mo = sm[w], so = ss[w];
      float mn = fmaxf(M, mo);
      Ssum = Ssum * __expf(M - mn) + so * __expf(mo - mn);
      M = mn;
    }
    float xid = x[ids[row]];
    surp[row] = (M + __logf(Ssum) - xid) * 1.4426950408889634f * mask[row];
  }
}

// ---------------- Kernel 2: x_proj (PERMUTED: col 4*unit + bitrev2(gate)) ----
// gate g in {i=0,f=1,g=2,o=3} -> slot {0,2,1,3}; so thread q of the LSTM
// (even q: unit q/2 gates (i,g); odd q: gates (f,o)) loads one float2 at 2q.
#define BM 64
#define BN 64
#define BK 32

__global__ __launch_bounds__(256) void xproj_kernel(
    const float* __restrict__ A,     // hidden_states [M,768]
    const float* __restrict__ surp,  // [M]
    const float* __restrict__ W,     // W_ih [400,769]
    const float* __restrict__ b_ih, const float* __restrict__ b_hh,
    float* __restrict__ xproj) {     // [M,400] permuted
  __shared__ float As[BK][BM];
  __shared__ float Bs[BK][BN];
  int tid = threadIdx.x;
  int m0 = blockIdx.x * BM;
  int n0 = blockIdx.y * BN;
  int tx = tid & 15, ty = tid >> 4;
  float acc[4][4] = {};
  for (int k0 = 0; k0 < H; k0 += BK) {
    #pragma unroll
    for (int l = 0; l < 2; ++l) {
      int idx = tid + l * 256;        // 0..511
      int row = idx >> 3;
      int kq = idx & 7;
      float4 v = *(const float4*)&A[(size_t)(m0 + row) * H + k0 + kq * 4];
      As[kq * 4 + 0][row] = v.x;
      As[kq * 4 + 1][row] = v.y;
      As[kq * 4 + 2][row] = v.z;
      As[kq * 4 + 3][row] = v.w;
    }
    #pragma unroll
    for (int l = 0; l < 8; ++l) {
      int idx = tid + l * 256;        // 0..2047
      int n = idx >> 5;
      int kk = idx & 31;
      int gn = n0 + n;
      Bs[kk][n] = (gn < G4) ? W[(size_t)gn * (H + 1) + k0 + kk] : 0.0f;
    }
    __syncthreads();
    #pragma unroll
    for (int k = 0; k < BK; ++k) {
      float4 a = *(const float4*)&As[k][ty * 4];
      float4 bq = *(const float4*)&Bs[k][tx * 4];
      float av[4] = {a.x, a.y, a.z, a.w};
      float bv[4] = {bq.x, bq.y, bq.z, bq.w};
      #pragma unroll
      for (int i = 0; i < 4; ++i)
        #pragma unroll
        for (int j = 0; j < 4; ++j)
          acc[i][j] += av[i] * bv[j];
    }
    __syncthreads();
  }
  #pragma unroll
  for (int i = 0; i < 4; ++i) {
    int gm = m0 + ty * 4 + i;
    float sv = surp[gm];
    #pragma unroll
    for (int j = 0; j < 4; ++j) {
      int gn = n0 + tx * 4 + j;   // gate-row index r = g*100 + k
      if (gn < G4) {
        float val = acc[i][j] + sv * W[(size_t)gn * (H + 1) + H] + b_ih[gn] + b_hh[gn];
        int g = gn / HID, k = gn % HID;
        int pn = 4 * k + (((g & 1) << 1) | (g >> 1));   // bitrev2(g)
        xproj[(size_t)gm * G4 + pn] = val;
      }
    }
  }
}

// ---------------- Kernel 3: LSTM scan via MFMA + classifier ------------------
// Phase A: gates_dot[400] = W_hh @ h via mfma_f32_16x16x32_f16.
//   M = 400 gate-interleaved rows (r = 4u+g <-> W_hh row g*100+u), K = 100
//   (padded 128 = 4 k-tiles), N = 16 (col 0 carries h; cols 1-15 zero).
//   A-fragments (W_hh) preloaded in REGISTERS (7 tiles x 4 kt x 4 VGPR/lane).
//   B-fragments: only lanes with col==0 read h from a 128-entry f16 LDS
//   buffer (4 x masked ds_read_b128/wave = ~64B/step vs 52KB for dot2).
//   C: lanes col==0 hold rows 16*tau + kg*4 + reg -> one float4 LDS write.
// Phase B: round-8's proven pair activation: thread q<200, unit k=q/2,
//   even q = (i,g), odd q = (f,o); gates from LDS + permuted-xproj float2
//   ring; 2 shfl_xor(1); c update; even lane writes h[k] (f16) back.
// Two raw (no-vmcnt-drain) barriers/step; single h & gates buffers.
__global__ __launch_bounds__(256, 1) void lstm_kernel(
    const float* __restrict__ xproj,  // [B,S,400] permuted cols
    const float* __restrict__ W_hh,   // [400,100]
    const float* __restrict__ sent,   // [B,3]
    const float* __restrict__ cls_W,  // [3,103]
    const float* __restrict__ cls_b,  // [3]
    float* __restrict__ out) {        // [B,3]
  int b = blockIdx.x;
  int tid = threadIdx.x;
  __shared__ __align__(16) _Float16 h_lds[128];   // h_{t-1}, pad 100..127 = 0
  __shared__ __align__(16) float gates_lds[G4];

  int lane = tid & 63;
  int w = tid >> 6;        // wave id 0..3
  int col = lane & 15;     // A row-in-tile / B col
  int kg = lane >> 4;      // k-subgroup 0..3

  // ---- A-fragments (constant across steps): wave w owns tiles 7w..7w+6
  // A[row = 16*tau + col][k = kt*32 + kg*8 + e]; row r=4u+g -> W_hh[g*100+u]
  half8_t afrag[NTILE][4];
  #pragma unroll
  for (int tt = 0; tt < NTILE; ++tt) {
    int tau = NTILE * w + tt;
    if (tau > 24) tau = 24;            // dummy tiles (wave 3), write-masked
    int row = 16 * tau + col;
    const float* wp = W_hh + (size_t)((row & 3) * HID + (row >> 2)) * HID;
    #pragma unroll
    for (int kt = 0; kt < 4; ++kt) {
      half8_t v;
      #pragma unroll
      for (int e = 0; e < 8; ++e) {
        int k = kt * 32 + kg * 8 + e;
        v[e] = (k < HID) ? (_Float16)wp[k] : (_Float16)0.f;
      }
      afrag[tt][kt] = v;
    }
  }

  // ---- phase-B identity (round-8 pair layout)
  bool active = tid < 200;
  int q = active ? tid : 199;          // clamp for uniform control flow
  int k = q >> 1;
  bool odd = (q & 1) != 0;
  int par = q & 1;

  float c_reg = 0.0f;
  if (tid < 128) h_lds[tid] = (_Float16)0;
  __syncthreads();

  const float* xp = xproj + (size_t)b * S * G4;
  float2 xr[PD];
  #pragma unroll
  for (int d = 0; d < PD; ++d)
    xr[d] = ((const float2*)(xp + (size_t)d * G4))[q];

  #pragma unroll 2
  for (int t = 0; t < S; ++t) {
    int slot = t & (PD - 1);                       // static under unroll 2
    float2 xv = xr[slot];
    {    // refill ring slot (global load stays in flight across raw barriers)
      int tp = (t + PD < S) ? (t + PD) : (S - 1);
      xr[slot] = ((const float2*)(xp + (size_t)tp * G4))[q];
    }

    // ---- phase A: MFMA gate dots
    half8_t bfrag[4];
    #pragma unroll
    for (int kt = 0; kt < 4; ++kt) {
      half8_t v = {0, 0, 0, 0, 0, 0, 0, 0};
      if (col == 0) v = *(const half8_t*)(h_lds + kt * 32 + kg * 8);
      bfrag[kt] = v;
    }
    #pragma unroll
    for (int tt = 0; tt < NTILE; ++tt) {
      float4_t acc = {0.f, 0.f, 0.f, 0.f};
      #pragma unroll
      for (int kt = 0; kt < 4; ++kt)
        acc = __builtin_amdgcn_mfma_f32_16x16x32_f16(afrag[tt][kt], bfrag[kt],
                                                     acc, 0, 0, 0);
      int tau = NTILE * w + tt;
      if (col == 0 && tau < 25)
        *(float4_t*)(gates_lds + 16 * tau + 4 * kg) = acc;
    }

    lds_barrier_();   // gates visible

    // ---- phase B: activations + cell update (round-8)
    float gA = gates_lds[4 * k + par];        // even: i ; odd: f
    float gB = gates_lds[4 * k + par + 2];    // even: g ; odd: o
    float aA = gA + xv.x;
    float aB = gB + xv.y;
    float vA = sigmoidf_(aA);                       // i or f
    float sB = sigmoidf_(odd ? aB : 2.0f * aB);
    float vB = odd ? sB : (2.0f * sB - 1.0f);       // o or tanh(g)
    float f_n = __shfl_xor(vA, 1);
    float o_n = __shfl_xor(vB, 1);
    c_reg = f_n * c_reg + vA * vB;                  // c = f*c + i*g
    float tc = 2.0f * sigmoidf_(2.0f * c_reg) - 1.0f;   // tanh(c)
    float h = o_n * tc;
    if (active && !odd) h_lds[k] = (_Float16)h;

    lds_barrier_();   // h_t visible for next step's B-fragments
  }

  if (tid < 3) {
    float acc = cls_b[tid];
    const float* cw = cls_W + tid * (HID + 3);
    #pragma unroll
    for (int j = 0; j < HID; ++j) acc += cw[j] * (float)h_lds[j];
    #pragma unroll
    for (int k2 = 0; k2 < 3; ++k2) acc += cw[HID + k2] * sent[b * 3 + k2];
    out[b * 3 + tid] = acc;
  }
}

extern "C" void kernel_launch(void* const* d_in, const int* in_sizes, int n_in,
                              void* d_out, int out_size, void* d_ws, size_t ws_size,
                              hipStream_t stream) {
  const int*   input_ids = (const int*)d_in[0];
  const float* mask      = (const float*)d_in[1];
  const float* sent      = (const float*)d_in[2];
  const float* hs        = (const float*)d_in[3];
  const float* logits    = (const float*)d_in[4];
  const float* W_ih      = (const float*)d_in[5];
  const float* W_hh      = (const float*)d_in[6];
  const float* b_ih      = (const float*)d_in[7];
  const float* b_hh      = (const float*)d_in[8];
  const float* cls_W     = (const float*)d_in[9];
  const float* cls_b     = (const float*)d_in[10];
  float* out = (float*)d_out;

  float* surp  = (float*)d_ws;            // M_TOT floats
  float* xproj = surp + M_TOT;            // M_TOT*400 floats

  surprisal_kernel<<<M_TOT, 256, 0, stream>>>(logits, input_ids, mask, surp);
  xproj_kernel<<<dim3(M_TOT / BM, (G4 + BN - 1) / BN), 256, 0, stream>>>(
      hs, surp, W_ih, b_ih, b_hh, xproj);
  lstm_kernel<<<B, 256, 0, stream>>>(xproj, W_hh, sent, cls_W, cls_b, out);
}

// Round 12
// 1580.969 us; speedup vs baseline: 1.1741x; 1.1741x over previous
//
#include <hip/hip_runtime.h>
#include <hip/hip_bf16.h>
#include <math.h>

#define B 4
#define S 2048
#define H 768
#define V 32000
#define HID 100
#define G4 400   // 4*HID
#define M_TOT (B*S)
#define PD 2     // xproj prefetch depth (steps)
#define NTILE 7  // M-tiles (of 16 rows) per wave: 25 tiles over 4 waves

typedef _Float16 half2_t __attribute__((ext_vector_type(2)));
typedef _Float16 half8_t __attribute__((ext_vector_type(8)));
typedef float float4_t __attribute__((ext_vector_type(4)));

__device__ __forceinline__ float sigmoidf_(float x) {
  return 1.0f / (1.0f + __expf(-x));
}

// Raw workgroup barrier: orders LDS (lgkmcnt drain) but does NOT drain vmcnt,
// so global prefetch loads stay in flight across steps.
__device__ __forceinline__ void lds_barrier_() {
  asm volatile("s_waitcnt lgkmcnt(0)" ::: "memory");
  __builtin_amdgcn_s_barrier();
  asm volatile("" ::: "memory");
}

// ---------------- Kernel 1: surprisal (online softmax + gather) --------------
__global__ __launch_bounds__(256) void surprisal_kernel(
    const float* __restrict__ logits, const int* __restrict__ ids,
    const float* __restrict__ mask, float* __restrict__ surp) {
  int row = blockIdx.x;
  const float* x = logits + (size_t)row * V;
  int tid = threadIdx.x;
  float m = -INFINITY, s = 0.0f;
  const float4* x4 = (const float4*)x;
  for (int i = tid; i < V / 4; i += 256) {
    float4 v = x4[i];
    float mv = fmaxf(fmaxf(v.x, v.y), fmaxf(v.z, v.w));
    if (mv > m) { s *= __expf(m - mv); m = mv; }
    s += __expf(v.x - m) + __expf(v.y - m) + __expf(v.z - m) + __expf(v.w - m);
  }
  #pragma unroll
  for (int off = 32; off > 0; off >>= 1) {
    float mo = __shfl_xor(m, off);
    float so = __shfl_xor(s, off);
    float mn = fmaxf(m, mo);
    s = s * __expf(m - mn) + so * __expf(mo - mn);
    m = mn;
  }
  __shared__ float sm[4], ss[4];
  int wid = tid >> 6, lane = tid & 63;
  if (lane == 0) { sm[wid] = m; ss[wid] = s; }
  __syncthreads();
  if (tid == 0) {
    float M = sm[0], Ssum = ss[0];
    #pragma unroll
    for (int w = 1; w < 4; ++w) {
      float mo = sm[w], so = ss[w];
      float mn = fmaxf(M, mo);
      Ssum = Ssum * __expf(M - mn) + so * __expf(mo - mn);
      M = mn;
    }
    float xid = x[ids[row]];
    surp[row] = (M + __logf(Ssum) - xid) * 1.4426950408889634f * mask[row];
  }
}

// ---------------- Kernel 2: x_proj (PERMUTED: col 4*unit + gate, natural) ----
#define BM 64
#define BN 64
#define BK 32

__global__ __launch_bounds__(256) void xproj_kernel(
    const float* __restrict__ A,     // hidden_states [M,768]
    const float* __restrict__ surp,  // [M]
    const float* __restrict__ W,     // W_ih [400,769]
    const float* __restrict__ b_ih, const float* __restrict__ b_hh,
    float* __restrict__ xproj) {     // [M,400] permuted: col = 4*unit + gate
  __shared__ float As[BK][BM];
  __shared__ float Bs[BK][BN];
  int tid = threadIdx.x;
  int m0 = blockIdx.x * BM;
  int n0 = blockIdx.y * BN;
  int tx = tid & 15, ty = tid >> 4;
  float acc[4][4] = {};
  for (int k0 = 0; k0 < H; k0 += BK) {
    #pragma unroll
    for (int l = 0; l < 2; ++l) {
      int idx = tid + l * 256;        // 0..511
      int row = idx >> 3;
      int kq = idx & 7;
      float4 v = *(const float4*)&A[(size_t)(m0 + row) * H + k0 + kq * 4];
      As[kq * 4 + 0][row] = v.x;
      As[kq * 4 + 1][row] = v.y;
      As[kq * 4 + 2][row] = v.z;
      As[kq * 4 + 3][row] = v.w;
    }
    #pragma unroll
    for (int l = 0; l < 8; ++l) {
      int idx = tid + l * 256;        // 0..2047
      int n = idx >> 5;
      int kk = idx & 31;
      int gn = n0 + n;
      Bs[kk][n] = (gn < G4) ? W[(size_t)gn * (H + 1) + k0 + kk] : 0.0f;
    }
    __syncthreads();
    #pragma unroll
    for (int k = 0; k < BK; ++k) {
      float4 a = *(const float4*)&As[k][ty * 4];
      float4 bq = *(const float4*)&Bs[k][tx * 4];
      float av[4] = {a.x, a.y, a.z, a.w};
      float bv[4] = {bq.x, bq.y, bq.z, bq.w};
      #pragma unroll
      for (int i = 0; i < 4; ++i)
        #pragma unroll
        for (int j = 0; j < 4; ++j)
          acc[i][j] += av[i] * bv[j];
    }
    __syncthreads();
  }
  #pragma unroll
  for (int i = 0; i < 4; ++i) {
    int gm = m0 + ty * 4 + i;
    float sv = surp[gm];
    #pragma unroll
    for (int j = 0; j < 4; ++j) {
      int gn = n0 + tx * 4 + j;   // gate-row index r = g*100 + k
      if (gn < G4) {
        float val = acc[i][j] + sv * W[(size_t)gn * (H + 1) + H] + b_ih[gn] + b_hh[gn];
        int pn = 4 * (gn % HID) + gn / HID;   // natural: 4*unit + gate
        xproj[(size_t)gm * G4 + pn] = val;
      }
    }
  }
}

// ---------------- Kernel 3: LSTM scan via MFMA, single-phase -----------------
// gates = W_hh @ h via mfma_f32_16x16x32_f16, M=400 rows (A-row R=16tau+4kg+g
// <-> W_hh row g*100+u, u=4tau+kg), K=100 (pad 128 = 4 k-tiles), B broadcast
// to ALL 16 cols (B[k][col]=h[k]) so every column of C carries the gates.
// Lane (col=c<7, kg) of wave w then owns unit u=4*(7w+c)+kg with all four
// gate pre-activations in its 4 C-regs -> does the ENTIRE cell update
// locally (no gates buffer, no shuffles) and writes h[u] (f16). ONE raw
// barrier + ONE LDS round-trip (h, double-buffered) per step. A-fragments
// pinned in VGPRs via asm (r11's VGPR=108 showed the compiler rematerialized
// the W_hh loads per-step without the pin). xproj permuted 4u+g -> one
// float4 bias load per activation lane, PD=2 ring.
__global__ __launch_bounds__(256, 1) void lstm_kernel(
    const float* __restrict__ xproj,  // [B,S,400] permuted cols (4u+g)
    const float* __restrict__ W_hh,   // [400,100]
    const float* __restrict__ sent,   // [B,3]
    const float* __restrict__ cls_W,  // [3,103]
    const float* __restrict__ cls_b,  // [3]
    float* __restrict__ out) {        // [B,3]
  int b = blockIdx.x;
  int tid = threadIdx.x;
  __shared__ __align__(16) _Float16 hb[2][128];   // pad 100..127 stays 0

  int lane = tid & 63;
  int w = tid >> 6;        // wave id 0..3
  int col = lane & 15;     // A row-in-tile / B col / C col
  int kg = lane >> 4;      // k-subgroup 0..3

  // ---- A-fragments (constant): wave w owns tiles 7w..7w+6 (clamped)
  half8_t afrag[NTILE][4];
  #pragma unroll
  for (int tt = 0; tt < NTILE; ++tt) {
    int tau = NTILE * w + tt;
    if (tau > 24) tau = 24;            // wave-3 dummy tiles (write-masked)
    int row = 16 * tau + col;          // global A-row R
    const float* wp = W_hh + (size_t)((row & 3) * HID + (row >> 2)) * HID;
    #pragma unroll
    for (int kt = 0; kt < 4; ++kt) {
      half8_t v;
      #pragma unroll
      for (int e = 0; e < 8; ++e) {
        int k = kt * 32 + kg * 8 + e;
        v[e] = (k < HID) ? (_Float16)wp[k] : (_Float16)0.f;
      }
      afrag[tt][kt] = v;
    }
  }
  // pin fragments in VGPRs: asm output is not rematerializable
  #pragma unroll
  for (int tt = 0; tt < NTILE; ++tt)
    #pragma unroll
    for (int kt = 0; kt < 4; ++kt) {
      float4_t tmp = __builtin_bit_cast(float4_t, afrag[tt][kt]);
      asm volatile("" : "+v"(tmp));
      afrag[tt][kt] = __builtin_bit_cast(half8_t, tmp);
    }

  // ---- activation-lane identity
  int tau_act = NTILE * w + col;            // tile this lane activates (col<7)
  bool actv = (col < NTILE) && (tau_act <= 24);
  int u = 4 * tau_act + kg;                 // unit index (valid when actv)
  float c_reg = 0.0f;

  if (tid < 128) { hb[0][tid] = (_Float16)0; hb[1][tid] = (_Float16)0; }
  __syncthreads();

  const float* xp = xproj + (size_t)b * S * G4;
  float4 xr[PD];
  if (actv) {
    #pragma unroll
    for (int d = 0; d < PD; ++d)
      xr[d] = *(const float4*)(xp + (size_t)d * G4 + 4 * u);
  }

  #pragma unroll 2
  for (int t = 0; t < S; ++t) {
    int slot = t & (PD - 1);                       // static under unroll 2
    const _Float16* hr = hb[(t + 1) & 1];          // h_{t-1}
    _Float16* hw = hb[t & 1];                      // h_t

    float4 xv = xr[slot];
    if (actv) {    // refill ring (stays in flight across raw barriers)
      int tp = (t + PD < S) ? (t + PD) : (S - 1);
      xr[slot] = *(const float4*)(xp + (size_t)tp * G4 + 4 * u);
    }

    // B-fragments: broadcast h to all 16 cols (uniform addr per 16-lane grp)
    half8_t bfrag[4];
    #pragma unroll
    for (int kt = 0; kt < 4; ++kt)
      bfrag[kt] = *(const half8_t*)(hr + kt * 32 + kg * 8);

    // 28 MFMA, kt-outer / tt-inner -> 7 independent chains
    float4_t acc[NTILE];
    #pragma unroll
    for (int tt = 0; tt < NTILE; ++tt) acc[tt] = float4_t{0.f, 0.f, 0.f, 0.f};
    #pragma unroll
    for (int kt = 0; kt < 4; ++kt)
      #pragma unroll
      for (int tt = 0; tt < NTILE; ++tt)
        acc[tt] = __builtin_amdgcn_mfma_f32_16x16x32_f16(afrag[tt][kt],
                                                         bfrag[kt], acc[tt], 0, 0, 0);

    // static select of this lane's tile (no dynamic indexing -> no scratch)
    float4_t g4 = acc[0];
    #pragma unroll
    for (int tt = 1; tt < NTILE; ++tt)
      if (col == tt) g4 = acc[tt];

    if (actv) {
      float ai = g4[0] + xv.x;
      float af = g4[1] + xv.y;
      float ag = g4[2] + xv.z;
      float ao = g4[3] + xv.w;
      float ig = sigmoidf_(ai);
      float fg = sigmoidf_(af);
      float gg = 2.0f * sigmoidf_(2.0f * ag) - 1.0f;   // tanh(g)
      float og = sigmoidf_(ao);
      c_reg = fg * c_reg + ig * gg;
      float tc = 2.0f * sigmoidf_(2.0f * c_reg) - 1.0f; // tanh(c)
      hw[u] = (_Float16)(og * tc);
    }

    lds_barrier_();   // h_t visible for next step's B-fragments
  }

  // final h (t = S-1 odd) is in hb[1]
  if (tid < 3) {
    float acc = cls_b[tid];
    const float* cw = cls_W + tid * (HID + 3);
    #pragma unroll
    for (int j = 0; j < HID; ++j) acc += cw[j] * (float)hb[1][j];
    #pragma unroll
    for (int k2 = 0; k2 < 3; ++k2) acc += cw[HID + k2] * sent[b * 3 + k2];
    out[b * 3 + tid] = acc;
  }
}

extern "C" void kernel_launch(void* const* d_in, const int* in_sizes, int n_in,
                              void* d_out, int out_size, void* d_ws, size_t ws_size,
                              hipStream_t stream) {
  const int*   input_ids = (const int*)d_in[0];
  const float* mask      = (const float*)d_in[1];
  const float* sent      = (const float*)d_in[2];
  const float* hs        = (const float*)d_in[3];
  const float* logits    = (const float*)d_in[4];
  const float* W_ih      = (const float*)d_in[5];
  const float* W_hh      = (const float*)d_in[6];
  const float* b_ih      = (const float*)d_in[7];
  const float* b_hh      = (const float*)d_in[8];
  const float* cls_W     = (const float*)d_in[9];
  const float* cls_b     = (const float*)d_in[10];
  float* out = (float*)d_out;

  float* surp  = (float*)d_ws;            // M_TOT floats
  float* xproj = surp + M_TOT;            // M_TOT*400 floats

  surprisal_kernel<<<M_TOT, 256, 0, stream>>>(logits, input_ids, mask, surp);
  xproj_kernel<<<dim3(M_TOT / BM, (G4 + BN - 1) / BN), 256, 0, stream>>>(
      hs, surp, W_ih, b_ih, b_hh, xproj);
  lstm_kernel<<<B, 256, 0, stream>>>(xproj, W_hh, sent, cls_W, cls_b, out);
}

// Round 13
// 1551.579 us; speedup vs baseline: 1.1963x; 1.0189x over previous
//
#include <hip/hip_runtime.h>
#include <hip/hip_bf16.h>
#include <math.h>

#define B 4
#define S 2048
#define H 768
#define V 32000
#define HID 100
#define G4 400   // 4*HID
#define M_TOT (B*S)
#define CH 16    // xproj staging chunk (steps)

typedef _Float16 half2_t __attribute__((ext_vector_type(2)));
typedef _Float16 half8_t __attribute__((ext_vector_type(8)));

__device__ __forceinline__ float fdot2_(half2_t a, half2_t b, float c) {
#if __has_builtin(__builtin_amdgcn_fdot2)
  return __builtin_amdgcn_fdot2(a, b, c, false);
#else
  return c + (float)a[0] * (float)b[0] + (float)a[1] * (float)b[1];
#endif
}

__device__ __forceinline__ float sigmoidf_(float x) {
  return 1.0f / (1.0f + __expf(-x));
}

// Raw workgroup barrier (orders LDS; any conservative vmcnt drain it causes is
// amortized by the chunked burst-prefetch structure).
__device__ __forceinline__ void lds_barrier_() {
  asm volatile("s_waitcnt lgkmcnt(0)" ::: "memory");
  __builtin_amdgcn_s_barrier();
  asm volatile("" ::: "memory");
}

// ---------------- Kernel 1: surprisal (online softmax + gather) --------------
__global__ __launch_bounds__(256) void surprisal_kernel(
    const float* __restrict__ logits, const int* __restrict__ ids,
    const float* __restrict__ mask, float* __restrict__ surp) {
  int row = blockIdx.x;
  const float* x = logits + (size_t)row * V;
  int tid = threadIdx.x;
  float m = -INFINITY, s = 0.0f;
  const float4* x4 = (const float4*)x;
  for (int i = tid; i < V / 4; i += 256) {
    float4 v = x4[i];
    float mv = fmaxf(fmaxf(v.x, v.y), fmaxf(v.z, v.w));
    if (mv > m) { s *= __expf(m - mv); m = mv; }
    s += __expf(v.x - m) + __expf(v.y - m) + __expf(v.z - m) + __expf(v.w - m);
  }
  #pragma unroll
  for (int off = 32; off > 0; off >>= 1) {
    float mo = __shfl_xor(m, off);
    float so = __shfl_xor(s, off);
    float mn = fmaxf(m, mo);
    s = s * __expf(m - mn) + so * __expf(mo - mn);
    m = mn;
  }
  __shared__ float sm[4], ss[4];
  int wid = tid >> 6, lane = tid & 63;
  if (lane == 0) { sm[wid] = m; ss[wid] = s; }
  __syncthreads();
  if (tid == 0) {
    float M = sm[0], Ssum = ss[0];
    #pragma unroll
    for (int w = 1; w < 4; ++w) {
      float mo = sm[w], so = ss[w];
      float mn = fmaxf(M, mo);
      Ssum = Ssum * __expf(M - mn) + so * __expf(mo - mn);
      M = mn;
    }
    float xid = x[ids[row]];
    surp[row] = (M + __logf(Ssum) - xid) * 1.4426950408889634f * mask[row];
  }
}

// ---------------- Kernel 2: x_proj (PERMUTED: col 4*unit + bitrev2(gate)) ----
// gate g in {i=0,f=1,g=2,o=3} -> slot {0,2,1,3}; so thread q of the LSTM
// (even q: unit q/2 gates (i,g); odd q: gates (f,o)) loads one float2 at 2q.
#define BM 64
#define BN 64
#define BK 32

__global__ __launch_bounds__(256) void xproj_kernel(
    const float* __restrict__ A,     // hidden_states [M,768]
    const float* __restrict__ surp,  // [M]
    const float* __restrict__ W,     // W_ih [400,769]
    const float* __restrict__ b_ih, const float* __restrict__ b_hh,
    float* __restrict__ xproj) {     // [M,400] permuted
  __shared__ float As[BK][BM];
  __shared__ float Bs[BK][BN];
  int tid = threadIdx.x;
  int m0 = blockIdx.x * BM;
  int n0 = blockIdx.y * BN;
  int tx = tid & 15, ty = tid >> 4;
  float acc[4][4] = {};
  for (int k0 = 0; k0 < H; k0 += BK) {
    #pragma unroll
    for (int l = 0; l < 2; ++l) {
      int idx = tid + l * 256;        // 0..511
      int row = idx >> 3;
      int kq = idx & 7;
      float4 v = *(const float4*)&A[(size_t)(m0 + row) * H + k0 + kq * 4];
      As[kq * 4 + 0][row] = v.x;
      As[kq * 4 + 1][row] = v.y;
      As[kq * 4 + 2][row] = v.z;
      As[kq * 4 + 3][row] = v.w;
    }
    #pragma unroll
    for (int l = 0; l < 8; ++l) {
      int idx = tid + l * 256;        // 0..2047
      int n = idx >> 5;
      int kk = idx & 31;
      int gn = n0 + n;
      Bs[kk][n] = (gn < G4) ? W[(size_t)gn * (H + 1) + k0 + kk] : 0.0f;
    }
    __syncthreads();
    #pragma unroll
    for (int k = 0; k < BK; ++k) {
      float4 a = *(const float4*)&As[k][ty * 4];
      float4 bq = *(const float4*)&Bs[k][tx * 4];
      float av[4] = {a.x, a.y, a.z, a.w};
      float bv[4] = {bq.x, bq.y, bq.z, bq.w};
      #pragma unroll
      for (int i = 0; i < 4; ++i)
        #pragma unroll
        for (int j = 0; j < 4; ++j)
          acc[i][j] += av[i] * bv[j];
    }
    __syncthreads();
  }
  #pragma unroll
  for (int i = 0; i < 4; ++i) {
    int gm = m0 + ty * 4 + i;
    float sv = surp[gm];
    #pragma unroll
    for (int j = 0; j < 4; ++j) {
      int gn = n0 + tx * 4 + j;   // gate-row index r = g*100 + k
      if (gn < G4) {
        float val = acc[i][j] + sv * W[(size_t)gn * (H + 1) + H] + b_ih[gn] + b_hh[gn];
        int g = gn / HID, k = gn % HID;
        int pn = 4 * k + (((g & 1) << 1) | (g >> 1));   // bitrev2(g)
        xproj[(size_t)gm * G4 + pn] = val;
      }
    }
  }
}

// ---------------- Kernel 3: LSTM scan + classifier ---------------------------
// Round-8 pair structure (best known: 1051 us) with ONE change: the xproj
// feed is CHUNK-STAGED through LDS instead of a per-step prefetch ring.
//   - at chunk start (t%16==0): burst-issue 16 coalesced float2 loads into
//     registers (static-indexed). Only the FIRST barrier after this sees
//     outstanding vmem -> one amortized drain per 16 steps instead of an
//     exposed global latency every step (r5-r12's hidden cost: conservative
//     vmcnt(0) drains at each barrier).
//   - at chunk end (t%16==15): ds_write the 16 float2 into the inactive half
//     of a double-buffered LDS chunk (vmcnt wait is free; loads are 15 steps
//     old). Per-step consumption = one dynamically-indexed 8B LDS read.
// Core per step (unchanged from r8): thread q<200 owns two gate rows of unit
// q/2 (even q -> (i,g), odd -> (f,o)) as half2 in regs; 13 uniform
// ds_read_b128 h-broadcast; 104 v_dot2_f32_f16; local activations; two
// shfl_xor(1); c update; even lane writes h (f16); one raw barrier.
__global__ __launch_bounds__(256, 1) void lstm_kernel(
    const float* __restrict__ xproj,  // [B,S,400] permuted cols
    const float* __restrict__ W_hh,   // [400,100]
    const float* __restrict__ sent,   // [B,3]
    const float* __restrict__ cls_W,  // [3,103]
    const float* __restrict__ cls_b,  // [3]
    float* __restrict__ out) {        // [B,3]
  int b = blockIdx.x;
  int tid = threadIdx.x;
  __shared__ __align__(16) _Float16 hb0[104];
  __shared__ __align__(16) _Float16 hb1[104];
  __shared__ __align__(16) float xs[2][CH * G4];   // 2 x 25.6 KB

  bool active = tid < 200;
  int q = active ? tid : 199;          // clamp for uniform control flow
  int k = q >> 1;
  bool odd = (q & 1) != 0;
  int rA = odd ? (HID + k) : k;                  // f : i
  int rB = odd ? (3 * HID + k) : (2 * HID + k);  // o : g

  half2_t wA[52], wB[52];
  {
    const float* pA = W_hh + (size_t)rA * HID;
    const float* pB = W_hh + (size_t)rB * HID;
    #pragma unroll
    for (int j = 0; j < 50; ++j) {
      wA[j] = half2_t{(_Float16)pA[2 * j], (_Float16)pA[2 * j + 1]};
      wB[j] = half2_t{(_Float16)pB[2 * j], (_Float16)pB[2 * j + 1]};
    }
    #pragma unroll
    for (int j = 50; j < 52; ++j) { wA[j] = half2_t{0, 0}; wB[j] = half2_t{0, 0}; }
  }

  float c_reg = 0.0f;
  if (tid < 104) { hb0[tid] = (_Float16)0; hb1[tid] = (_Float16)0; }

  const float* xp = xproj + (size_t)b * S * G4;
  float2 xreg[CH];

  // prologue: stage chunk 0 into xs[0]
  #pragma unroll
  for (int j = 0; j < CH; ++j)
    xreg[j] = ((const float2*)(xp + (size_t)j * G4))[q];
  #pragma unroll
  for (int j = 0; j < CH; ++j)
    *(float2*)&xs[0][j * G4 + 2 * q] = xreg[j];
  __syncthreads();

  #pragma unroll 2
  for (int t = 0; t < S; ++t) {
    const _Float16* hr = (t & 1) ? hb0 : hb1;
    _Float16* hw = (t & 1) ? hb1 : hb0;

    // chunk start: burst-issue next chunk's loads (15 steps of slack)
    if ((t & (CH - 1)) == 0) {
      int tn = t + CH;
      #pragma unroll
      for (int j = 0; j < CH; ++j) {
        int tl = tn + j; if (tl > S - 1) tl = S - 1;
        xreg[j] = ((const float2*)(xp + (size_t)tl * G4))[q];
      }
    }

    // per-step bias from staged LDS chunk (dynamic index OK in LDS)
    float2 xv = *(const float2*)&xs[(t >> 4) & 1][(t & (CH - 1)) * G4 + 2 * q];

    float a0 = 0.f, a1 = 0.f, b0 = 0.f, b1 = 0.f;
    #pragma unroll
    for (int j = 0; j < 13; ++j) {
      half8_t hv = *(const half8_t*)(hr + 8 * j);  // uniform addr -> broadcast
      half2_t h0 = {hv[0], hv[1]}, h1 = {hv[2], hv[3]};
      half2_t h2 = {hv[4], hv[5]}, h3 = {hv[6], hv[7]};
      a0 = fdot2_(wA[4 * j + 0], h0, a0);
      b0 = fdot2_(wB[4 * j + 0], h0, b0);
      a1 = fdot2_(wA[4 * j + 1], h1, a1);
      b1 = fdot2_(wB[4 * j + 1], h1, b1);
      a0 = fdot2_(wA[4 * j + 2], h2, a0);
      b0 = fdot2_(wB[4 * j + 2], h2, b0);
      a1 = fdot2_(wA[4 * j + 3], h3, a1);
      b1 = fdot2_(wB[4 * j + 3], h3, b1);
    }
    float aA = a0 + a1 + xv.x;   // even: i_pre ; odd: f_pre
    float aB = b0 + b1 + xv.y;   // even: g_pre ; odd: o_pre

    // local activations (uniform instruction stream, per-lane selects):
    float vA = sigmoidf_(aA);                       // i or f
    float sB = sigmoidf_(odd ? aB : 2.0f * aB);
    float vB = odd ? sB : (2.0f * sB - 1.0f);       // o or tanh(g)

    // two independent pair-exchanges: even lane receives f and o
    float f_n = __shfl_xor(vA, 1);
    float o_n = __shfl_xor(vB, 1);

    // cell update on even lanes: c = f*c + i*g ; h = o * tanh(c)
    c_reg = f_n * c_reg + vA * vB;
    float tc = 2.0f * sigmoidf_(2.0f * c_reg) - 1.0f;
    float h = o_n * tc;
    if (active && !odd) hw[k] = (_Float16)h;

    // chunk end: commit staged regs to the inactive LDS chunk half
    if ((t & (CH - 1)) == (CH - 1)) {
      float* xd = xs[((t >> 4) + 1) & 1];
      #pragma unroll
      for (int j = 0; j < CH; ++j)
        *(float2*)&xd[j * G4 + 2 * q] = xreg[j];
    }

    lds_barrier_();   // h_t (and any chunk commit) visible
  }

  // S even -> final h (t = S-1, odd) is in hb1
  if (tid < 3) {
    float acc = cls_b[tid];
    const float* cw = cls_W + tid * (HID + 3);
    #pragma unroll
    for (int j = 0; j < HID; ++j) acc += cw[j] * (float)hb1[j];
    #pragma unroll
    for (int k2 = 0; k2 < 3; ++k2) acc += cw[HID + k2] * sent[b * 3 + k2];
    out[b * 3 + tid] = acc;
  }
}

extern "C" void kernel_launch(void* const* d_in, const int* in_sizes, int n_in,
                              void* d_out, int out_size, void* d_ws, size_t ws_size,
                              hipStream_t stream) {
  const int*   input_ids = (const int*)d_in[0];
  const float* mask      = (const float*)d_in[1];
  const float* sent      = (const float*)d_in[2];
  const float* hs        = (const float*)d_in[3];
  const float* logits    = (const float*)d_in[4];
  const float* W_ih      = (const float*)d_in[5];
  const float* W_hh      = (const float*)d_in[6];
  const float* b_ih      = (const float*)d_in[7];
  const float* b_hh      = (const float*)d_in[8];
  const float* cls_W     = (const float*)d_in[9];
  const float* cls_b     = (const float*)d_in[10];
  float* out = (float*)d_out;

  float* surp  = (float*)d_ws;            // M_TOT floats
  float* xproj = surp + M_TOT;            // M_TOT*400 floats

  surprisal_kernel<<<M_TOT, 256, 0, stream>>>(logits, input_ids, mask, surp);
  xproj_kernel<<<dim3(M_TOT / BM, (G4 + BN - 1) / BN), 256, 0, stream>>>(
      hs, surp, W_ih, b_ih, b_hh, xproj);
  lstm_kernel<<<B, 256, 0, stream>>>(xproj, W_hh, sent, cls_W, cls_b, out);
}

// Round 14
// 1419.428 us; speedup vs baseline: 1.3077x; 1.0931x over previous
//
#include <hip/hip_runtime.h>
#include <hip/hip_bf16.h>
#include <math.h>

#define B 4
#define S 2048
#define H 768
#define V 32000
#define HID 100
#define G4 400   // 4*HID
#define M_TOT (B*S)
#define PD 2     // xproj prefetch depth (steps)

typedef _Float16 half2_t __attribute__((ext_vector_type(2)));
typedef _Float16 half8_t __attribute__((ext_vector_type(8)));

__device__ __forceinline__ float fdot2_(half2_t a, half2_t b, float c) {
#if __has_builtin(__builtin_amdgcn_fdot2)
  return __builtin_amdgcn_fdot2(a, b, c, false);
#else
  return c + (float)a[0] * (float)b[0] + (float)a[1] * (float)b[1];
#endif
}

__device__ __forceinline__ float sigmoidf_(float x) {
  return 1.0f / (1.0f + __expf(-x));
}

// Raw workgroup barrier: orders LDS (lgkmcnt drain) without forcing the
// compiler's full vmcnt(0)+expcnt drain of __syncthreads.
__device__ __forceinline__ void lds_barrier_() {
  asm volatile("s_waitcnt lgkmcnt(0)" ::: "memory");
  __builtin_amdgcn_s_barrier();
  asm volatile("" ::: "memory");
}

// ---------------- Kernel 1: FUSED surprisal + x_proj main GEMM ---------------
// Blocks [0, NGEMM): x_proj main GEMM (K=768, no surp term; biases folded;
//   writes PERMUTED col 4*unit + bitrev2(gate) like round-8).
// Blocks [NGEMM, NGEMM+M_TOT): surprisal rows (online softmax + gather).
// GEMM blocks first so they co-schedule with (and hide inside) the
// HBM-bound surprisal wave.
#define BM 64
#define BN 64
#define BK 32
#define NTM (M_TOT / BM)          // 128
#define NTN ((G4 + BN - 1) / BN)  // 7
#define NGEMM (NTM * NTN)         // 896

__global__ __launch_bounds__(256) void fused_pre_kernel(
    const float* __restrict__ logits, const int* __restrict__ ids,
    const float* __restrict__ mask, float* __restrict__ surp,
    const float* __restrict__ A,     // hidden_states [M,768]
    const float* __restrict__ W,     // W_ih [400,769]
    const float* __restrict__ b_ih, const float* __restrict__ b_hh,
    float* __restrict__ xproj) {     // [M,400] permuted
  __shared__ float smem[BK * BM + BK * BN];   // GEMM tiles (16 KB)
  int tid = threadIdx.x;

  if (blockIdx.x < NGEMM) {
    // ---------------- GEMM part ----------------
    float (*As)[BM] = (float(*)[BM])smem;
    float (*Bs)[BN] = (float(*)[BN])(smem + BK * BM);
    int bid = blockIdx.x;
    int m0 = (bid / NTN) * BM;
    int n0 = (bid % NTN) * BN;
    int tx = tid & 15, ty = tid >> 4;
    float acc[4][4] = {};
    for (int k0 = 0; k0 < H; k0 += BK) {
      #pragma unroll
      for (int l = 0; l < 2; ++l) {
        int idx = tid + l * 256;        // 0..511
        int row = idx >> 3;
        int kq = idx & 7;
        float4 v = *(const float4*)&A[(size_t)(m0 + row) * H + k0 + kq * 4];
        As[kq * 4 + 0][row] = v.x;
        As[kq * 4 + 1][row] = v.y;
        As[kq * 4 + 2][row] = v.z;
        As[kq * 4 + 3][row] = v.w;
      }
      #pragma unroll
      for (int l = 0; l < 8; ++l) {
        int idx = tid + l * 256;        // 0..2047
        int n = idx >> 5;
        int kk = idx & 31;
        int gn = n0 + n;
        Bs[kk][n] = (gn < G4) ? W[(size_t)gn * (H + 1) + k0 + kk] : 0.0f;
      }
      __syncthreads();
      #pragma unroll
      for (int k = 0; k < BK; ++k) {
        float4 a = *(const float4*)&As[k][ty * 4];
        float4 bq = *(const float4*)&Bs[k][tx * 4];
        float av[4] = {a.x, a.y, a.z, a.w};
        float bv[4] = {bq.x, bq.y, bq.z, bq.w};
        #pragma unroll
        for (int i = 0; i < 4; ++i)
          #pragma unroll
          for (int j = 0; j < 4; ++j)
            acc[i][j] += av[i] * bv[j];
      }
      __syncthreads();
    }
    #pragma unroll
    for (int i = 0; i < 4; ++i) {
      int gm = m0 + ty * 4 + i;
      #pragma unroll
      for (int j = 0; j < 4; ++j) {
        int gn = n0 + tx * 4 + j;   // gate-row index r = g*100 + k
        if (gn < G4) {
          float val = acc[i][j] + b_ih[gn] + b_hh[gn];
          int g = gn / HID, k = gn % HID;
          int pn = 4 * k + (((g & 1) << 1) | (g >> 1));   // bitrev2(g)
          xproj[(size_t)gm * G4 + pn] = val;
        }
      }
    }
  } else {
    // ---------------- surprisal part ----------------
    int row = blockIdx.x - NGEMM;
    const float* x = logits + (size_t)row * V;
    float m = -INFINITY, s = 0.0f;
    const float4* x4 = (const float4*)x;
    for (int i = tid; i < V / 4; i += 256) {
      float4 v = x4[i];
      float mv = fmaxf(fmaxf(v.x, v.y), fmaxf(v.z, v.w));
      if (mv > m) { s *= __expf(m - mv); m = mv; }
      s += __expf(v.x - m) + __expf(v.y - m) + __expf(v.z - m) + __expf(v.w - m);
    }
    #pragma unroll
    for (int off = 32; off > 0; off >>= 1) {
      float mo = __shfl_xor(m, off);
      float so = __shfl_xor(s, off);
      float mn = fmaxf(m, mo);
      s = s * __expf(m - mn) + so * __expf(mo - mn);
      m = mn;
    }
    __shared__ float sm[4], ss[4];
    int wid = tid >> 6, lane = tid & 63;
    if (lane == 0) { sm[wid] = m; ss[wid] = s; }
    __syncthreads();
    if (tid == 0) {
      float M = sm[0], Ssum = ss[0];
      #pragma unroll
      for (int w = 1; w < 4; ++w) {
        float mo = sm[w], so = ss[w];
        float mn = fmaxf(M, mo);
        Ssum = Ssum * __expf(M - mn) + so * __expf(mo - mn);
        M = mn;
      }
      float xid = x[ids[row]];
      surp[row] = (M + __logf(Ssum) - xid) * 1.4426950408889634f * mask[row];
    }
  }
}

// ---------------- Kernel 2: rank-1 surprisal column correction ---------------
// xproj[m, pn] += surp[m] * W_ih[gn, 768], pn = permuted col of gate-row gn.
__global__ __launch_bounds__(448) void rank1_kernel(
    const float* __restrict__ surp, const float* __restrict__ W,
    float* __restrict__ xproj) {
  int m = blockIdx.x;
  int pn = threadIdx.x;
  if (pn >= G4) return;
  int k = pn >> 2, slot = pn & 3;
  int g = ((slot & 1) << 1) | (slot >> 1);   // bitrev2 (involution)
  int gn = g * HID + k;
  float wl = W[(size_t)gn * (H + 1) + H];
  xproj[(size_t)m * G4 + pn] += surp[m] * wl;
}

// ---------------- Kernel 3: LSTM scan + classifier (round-8, best known) -----
// Thread q (q<200) owns TWO gate rows of unit k=q/2: even q -> (i,g) rows;
// odd q -> (f,o). Weights half2 in regs; 13 uniform ds_read_b128 h-broadcast;
// 104 v_dot2_f32_f16; local activations; two shfl_xor(1); c update; even lane
// writes h[k] (f16). One raw barrier/step; double-buffered h; PD=2 coalesced
// float2 xproj ring (permuted cols).
#define NH2 52          // 50 half2 + 2 zero-pad -> 13 x b128
__global__ __launch_bounds__(256, 1) void lstm_kernel(
    const float* __restrict__ xproj,  // [B,S,400] permuted cols
    const float* __restrict__ W_hh,   // [400,100]
    const float* __restrict__ sent,   // [B,3]
    const float* __restrict__ cls_W,  // [3,103]
    const float* __restrict__ cls_b,  // [3]
    float* __restrict__ out) {        // [B,3]
  int b = blockIdx.x;
  int tid = threadIdx.x;
  __shared__ __align__(16) _Float16 hb0[2 * NH2];
  __shared__ __align__(16) _Float16 hb1[2 * NH2];

  bool active = tid < 200;
  int q = active ? tid : 199;          // clamp for uniform control flow
  int k = q >> 1;
  bool odd = (q & 1) != 0;
  int rA = odd ? (HID + k) : k;                  // f : i
  int rB = odd ? (3 * HID + k) : (2 * HID + k);  // o : g

  half2_t wA[NH2], wB[NH2];
  {
    const float* pA = W_hh + (size_t)rA * HID;
    const float* pB = W_hh + (size_t)rB * HID;
    #pragma unroll
    for (int j = 0; j < 50; ++j) {
      wA[j] = half2_t{(_Float16)pA[2 * j], (_Float16)pA[2 * j + 1]};
      wB[j] = half2_t{(_Float16)pB[2 * j], (_Float16)pB[2 * j + 1]};
    }
    #pragma unroll
    for (int j = 50; j < NH2; ++j) { wA[j] = half2_t{0, 0}; wB[j] = half2_t{0, 0}; }
  }

  float c_reg = 0.0f;
  if (tid < 2 * NH2) { hb0[tid] = (_Float16)0; hb1[tid] = (_Float16)0; }
  __syncthreads();

  const float* xp = xproj + (size_t)b * S * G4;
  float2 xr[PD];
  #pragma unroll
  for (int d = 0; d < PD; ++d)
    xr[d] = ((const float2*)(xp + (size_t)d * G4))[q];

  #pragma unroll 2
  for (int t = 0; t < S; ++t) {
    int slot = t & (PD - 1);                       // static under unroll 2
    const half8_t* hr = (t & 1) ? (const half8_t*)hb0 : (const half8_t*)hb1;
    _Float16* hw = (t & 1) ? hb1 : hb0;

    float2 xv = xr[slot];
    // refill ring slot early (independent; stays in flight across barriers)
    {
      int tp = (t + PD < S) ? (t + PD) : (S - 1);
      xr[slot] = ((const float2*)(xp + (size_t)tp * G4))[q];
    }

    float a0 = 0.f, a1 = 0.f, b0 = 0.f, b1 = 0.f;
    #pragma unroll
    for (int j = 0; j < 13; ++j) {
      half8_t hv = hr[j];                          // uniform addr -> broadcast
      half2_t h0 = {hv[0], hv[1]}, h1 = {hv[2], hv[3]};
      half2_t h2 = {hv[4], hv[5]}, h3 = {hv[6], hv[7]};
      a0 = fdot2_(wA[4 * j + 0], h0, a0);
      b0 = fdot2_(wB[4 * j + 0], h0, b0);
      a1 = fdot2_(wA[4 * j + 1], h1, a1);
      b1 = fdot2_(wB[4 * j + 1], h1, b1);
      a0 = fdot2_(wA[4 * j + 2], h2, a0);
      b0 = fdot2_(wB[4 * j + 2], h2, b0);
      a1 = fdot2_(wA[4 * j + 3], h3, a1);
      b1 = fdot2_(wB[4 * j + 3], h3, b1);
    }
    float aA = a0 + a1 + xv.x;   // even: i_pre ; odd: f_pre
    float aB = b0 + b1 + xv.y;   // even: g_pre ; odd: o_pre

    // local activations (uniform instruction stream, per-lane selects):
    float vA = sigmoidf_(aA);                       // i or f
    float sB = sigmoidf_(odd ? aB : 2.0f * aB);
    float vB = odd ? sB : (2.0f * sB - 1.0f);       // o or tanh(g)

    // two independent pair-exchanges: even lane receives f and o
    float f_n = __shfl_xor(vA, 1);
    float o_n = __shfl_xor(vB, 1);

    // cell update on even lanes: c = f*c + i*g ; h = o * tanh(c)
    c_reg = f_n * c_reg + vA * vB;
    float tc = 2.0f * sigmoidf_(2.0f * c_reg) - 1.0f;
    float h = o_n * tc;
    if (active && !odd) hw[k] = (_Float16)h;

    lds_barrier_();   // h_t visible; next step writes the OTHER buffer
  }

  // S even -> final h (t = S-1, odd) is in hb1
  if (tid < 3) {
    float acc = cls_b[tid];
    const float* cw = cls_W + tid * (HID + 3);
    #pragma unroll
    for (int j = 0; j < HID; ++j) acc += cw[j] * (float)hb1[j];
    #pragma unroll
    for (int k2 = 0; k2 < 3; ++k2) acc += cw[HID + k2] * sent[b * 3 + k2];
    out[b * 3 + tid] = acc;
  }
}

extern "C" void kernel_launch(void* const* d_in, const int* in_sizes, int n_in,
                              void* d_out, int out_size, void* d_ws, size_t ws_size,
                              hipStream_t stream) {
  const int*   input_ids = (const int*)d_in[0];
  const float* mask      = (const float*)d_in[1];
  const float* sent      = (const float*)d_in[2];
  const float* hs        = (const float*)d_in[3];
  const float* logits    = (const float*)d_in[4];
  const float* W_ih      = (const float*)d_in[5];
  const float* W_hh      = (const float*)d_in[6];
  const float* b_ih      = (const float*)d_in[7];
  const float* b_hh      = (const float*)d_in[8];
  const float* cls_W     = (const float*)d_in[9];
  const float* cls_b     = (const float*)d_in[10];
  float* out = (float*)d_out;

  float* surp  = (float*)d_ws;            // M_TOT floats
  float* xproj = surp + M_TOT;            // M_TOT*400 floats

  fused_pre_kernel<<<NGEMM + M_TOT, 256, 0, stream>>>(
      logits, input_ids, mask, surp, hs, W_ih, b_ih, b_hh, xproj);
  rank1_kernel<<<M_TOT, 448, 0, stream>>>(surp, W_ih, xproj);
  lstm_kernel<<<B, 256, 0, stream>>>(xproj, W_hh, sent, cls_W, cls_b, out);
}